// Round 2
// baseline (69.529 us; speedup 1.0000x reference)
//
#include <hip/hip_runtime.h>
#include <math.h>

#define PI_F 3.14159265358979323846f
#define INV_2PI_D 0.15915494309189535

// intra-wave LDS ordering: DS pipe is in-order per wave; the waitcnt +
// memory clobber stops compiler reordering and guarantees completion.
#define LDSYNC() asm volatile("s_waitcnt lgkmcnt(0)" ::: "memory")

// bank/alignment swizzle: keeps low 2 bits (16B-aligned float4 slots),
// XORs slot bits [4:2] with higher address bits so every transpose phase
// spreads evenly over the 32 banks (<=2-way).
__device__ __forceinline__ int swz(int e) {
    return e ^ ((((e >> 5) ^ (e >> 7)) & 7) << 2);
}

__device__ __forceinline__ void bfly(float& ar, float& ai, float& br, float& bi,
                                     float wr, float wi) {
    const float tr = wr * br - wi * bi;
    const float ti = wr * bi + wi * br;
    br = ar - tr; bi = ai - ti;
    ar = ar + tr; ai = ai + ti;
}

__device__ __forceinline__ void fft_row(
    const float* __restrict__ xre, const float* __restrict__ xim,
    float* __restrict__ yre, float* __restrict__ yim,
    float* __restrict__ sre, float* __restrict__ sim, int row)
{
    const int lane = (int)(threadIdx.x & 63u);
    const size_t base = (size_t)row << 10;
    const int lin = lane << 4;

    float re[16], im[16];

    // ---- coalesced float4 loads: reg r holds work element rev10(lane*16+r)
#pragma unroll
    for (int q = 0; q < 4; ++q) {
        const float4 vr = *reinterpret_cast<const float4*>(xre + base + lin + 4*q);
        const float4 vi = *reinterpret_cast<const float4*>(xim + base + lin + 4*q);
        re[4*q+0] = vr.x; re[4*q+1] = vr.y; re[4*q+2] = vr.z; re[4*q+3] = vr.w;
        im[4*q+0] = vi.x; im[4*q+1] = vi.y; im[4*q+2] = vi.z; im[4*q+3] = vi.w;
    }

    const int rev6l = (int)(__brev((unsigned)lane) >> 26);
    const int REV4[16] = {0,8,4,12,2,10,6,14,1,9,5,13,3,11,7,15};

    // ---- T0: scatter (e = rev4(r)*64 + rev6(lane)) -> L1 (e = lane*16 + r)
#pragma unroll
    for (int r = 0; r < 16; ++r) {
        const int a = swz(REV4[r]*64 + rev6l);
        sre[a] = re[r]; sim[a] = im[r];
    }
    LDSYNC();
#pragma unroll
    for (int q = 0; q < 4; ++q) {
        const int a = swz(lin + 4*q);
        const float4 vr = *reinterpret_cast<const float4*>(sre + a);
        const float4 vi = *reinterpret_cast<const float4*>(sim + a);
        re[4*q+0] = vr.x; re[4*q+1] = vr.y; re[4*q+2] = vr.z; re[4*q+3] = vr.w;
        im[4*q+0] = vi.x; im[4*q+1] = vi.y; im[4*q+2] = vi.z; im[4*q+3] = vi.w;
    }
    LDSYNC();

    // ---- L1 stages s=1,2,4,8 ; k = r&(s-1), exact constant twiddles
    const float W8R[8] = {1.f, 0.9238795325112867f, 0.7071067811865476f,
                          0.3826834323650898f, 0.f, -0.3826834323650898f,
                          -0.7071067811865476f, -0.9238795325112867f};
    const float W8I[8] = {0.f, -0.3826834323650898f, -0.7071067811865476f,
                          -0.9238795325112867f, -1.f, -0.9238795325112867f,
                          -0.7071067811865476f, -0.3826834323650898f};
#pragma unroll
    for (int st = 0; st < 4; ++st) {
        const int S = 1 << st;
#pragma unroll
        for (int rl = 0; rl < 16; ++rl) {
            if (rl & S) continue;
            const int k8 = (rl & (S - 1)) * (8 >> st);
            bfly(re[rl], im[rl], re[rl | S], im[rl | S], W8R[k8], W8I[k8]);
        }
    }

    // ---- T1: L1 -> L3 (e = (lane>>4)*256 + r*16 + (lane&15))
#pragma unroll
    for (int q = 0; q < 4; ++q) {
        const int a = swz(lin + 4*q);
        *reinterpret_cast<float4*>(sre + a) = make_float4(re[4*q], re[4*q+1], re[4*q+2], re[4*q+3]);
        *reinterpret_cast<float4*>(sim + a) = make_float4(im[4*q], im[4*q+1], im[4*q+2], im[4*q+3]);
    }
    LDSYNC();
    const int hi = (lane >> 4) << 8;
    const int lo = lane & 15;
#pragma unroll
    for (int r = 0; r < 16; ++r) {
        const int a = swz(hi + (r << 4) + lo);
        re[r] = sre[a]; im[r] = sim[a];
    }
    LDSYNC();

    // ---- L3 twiddles: 8 sincos for s=128, squared down to s=64,32,16
    const float l16f = (float)lo;
    float c8a[8], s8a[8];
#pragma unroll
    for (int m = 0; m < 8; ++m) {
        const float ang = -(PI_F / 128.0f) * (16.0f * (float)m + l16f);
        __sincosf(ang, &s8a[m], &c8a[m]);
    }
    float c4a[4], s4a[4];
#pragma unroll
    for (int m = 0; m < 4; ++m) { c4a[m] = c8a[m]*c8a[m] - s8a[m]*s8a[m]; s4a[m] = 2.0f*c8a[m]*s8a[m]; }
    float c2a[2], s2a[2];
#pragma unroll
    for (int m = 0; m < 2; ++m) { c2a[m] = c4a[m]*c4a[m] - s4a[m]*s4a[m]; s2a[m] = 2.0f*c4a[m]*s4a[m]; }
    const float c1a = c2a[0]*c2a[0] - s2a[0]*s2a[0];
    const float s1a = 2.0f*c2a[0]*s2a[0];

    // s=16
#pragma unroll
    for (int rl = 0; rl < 16; ++rl) if (!(rl & 1))
        bfly(re[rl], im[rl], re[rl|1], im[rl|1], c1a, s1a);
    // s=32
#pragma unroll
    for (int rl = 0; rl < 16; ++rl) if (!(rl & 2))
        bfly(re[rl], im[rl], re[rl|2], im[rl|2], c2a[rl & 1], s2a[rl & 1]);
    // s=64
#pragma unroll
    for (int rl = 0; rl < 16; ++rl) if (!(rl & 4))
        bfly(re[rl], im[rl], re[rl|4], im[rl|4], c4a[rl & 3], s4a[rl & 3]);
    // s=128
#pragma unroll
    for (int rl = 0; rl < 16; ++rl) if (!(rl & 8))
        bfly(re[rl], im[rl], re[rl|8], im[rl|8], c8a[rl & 7], s8a[rl & 7]);

    // ---- T2: L3 -> L2 (e = r*64 + lane)
#pragma unroll
    for (int r = 0; r < 16; ++r) {
        const int a = swz(hi + (r << 4) + lo);
        sre[a] = re[r]; sim[a] = im[r];
    }
    LDSYNC();
#pragma unroll
    for (int r = 0; r < 16; ++r) {
        const int a = swz((r << 6) + lane);
        re[r] = sre[a]; im[r] = sim[a];
    }
    LDSYNC();

    // ---- L2 twiddles: 8 sincos for s=512, squared for s=256
    const float lf = (float)lane;
    float cz8[8], sz8[8];
#pragma unroll
    for (int m = 0; m < 8; ++m) {
        const float ang = -(PI_F / 512.0f) * (64.0f * (float)m + lf);
        __sincosf(ang, &sz8[m], &cz8[m]);
    }
    float cz4[4], sz4[4];
#pragma unroll
    for (int m = 0; m < 4; ++m) { cz4[m] = cz8[m]*cz8[m] - sz8[m]*sz8[m]; sz4[m] = 2.0f*cz8[m]*sz8[m]; }

    // s=256
#pragma unroll
    for (int rl = 0; rl < 16; ++rl) if (!(rl & 4))
        bfly(re[rl], im[rl], re[rl|4], im[rl|4], cz4[rl & 3], sz4[rl & 3]);
    // s=512
#pragma unroll
    for (int rl = 0; rl < 16; ++rl) if (!(rl & 8))
        bfly(re[rl], im[rl], re[rl|8], im[rl|8], cz8[rl & 7], sz8[rl & 7]);

    // ---- T3: L2 -> linear, then float4 stores
#pragma unroll
    for (int r = 0; r < 16; ++r) {
        const int a = swz((r << 6) + lane);
        sre[a] = re[r]; sim[a] = im[r];
    }
    LDSYNC();
#pragma unroll
    for (int q = 0; q < 4; ++q) {
        const int a = swz(lin + 4*q);
        const float4 vr = *reinterpret_cast<const float4*>(sre + a);
        const float4 vi = *reinterpret_cast<const float4*>(sim + a);
        *reinterpret_cast<float4*>(yre + base + lin + 4*q) = vr;
        *reinterpret_cast<float4*>(yim + base + lin + 4*q) = vi;
    }
}

__device__ void z_eval(const float* __restrict__ tin, float* __restrict__ zout,
                       int zblock, int n, float* __restrict__ buf)
{
    float* slog = buf;
    float* srsq = buf + 1024;
    for (int i = (int)threadIdx.x; i < 1024; i += 256) {
        const double nd = (double)(i + 1);
        slog[i] = (float)log(nd);            // correctly-rounded fl32(log n)
        srsq[i] = (float)(1.0 / sqrt(nd));
    }
    __syncthreads();

    const int gid = zblock * 256 + (int)threadIdx.x;
    if (gid >= n) return;

    const float t  = tin[gid];
    const float th = __fmul_rn(t, 0.5f);
    const float logt = (float)log((double)t);
    float theta = __fsub_rn(__fsub_rn(__fmul_rn(th, __fsub_rn(logt, 1.8378770664093453f)), th),
                            0.39269908169872414f);
    theta = __fadd_rn(theta, __fdiv_rn(1.0f, __fmul_rn(48.0f, t)));

    int nt = (int)sqrtf(__fdiv_rn(t, 6.283185307179586f));
    nt = min(max(nt, 10), 1024);

    float acc = 0.0f;
    for (int i = 0; i < nt; ++i) {
        const float p = __fsub_rn(__fmul_rn(t, slog[i]), theta);
        const double rev = (double)p * INV_2PI_D;
        const double fr  = rev - rint(rev);            // |fr| <= 0.5 revolutions
        const float  c   = __builtin_amdgcn_cosf((float)fr);
        acc = __fmaf_rn(srsq[i], c, acc);
    }
    zout[gid] = __fmul_rn(2.0f, acc);
}

__global__ __launch_bounds__(256, 5) void fused_kernel(
    const float* __restrict__ xre, const float* __restrict__ xim,
    const float* __restrict__ tin,
    float* __restrict__ yre, float* __restrict__ yim, float* __restrict__ zout,
    int nf_blocks, int nrows, int nz)
{
    __shared__ float s_re[4][1024];
    __shared__ float s_im[4][1024];

    const int b = (int)blockIdx.x;
    if (b < nf_blocks) {
        const int wid = (int)(threadIdx.x >> 6);
        const int row = (b << 2) | wid;
        if (row < nrows)
            fft_row(xre, xim, yre, yim, s_re[wid], s_im[wid], row);
    } else {
        z_eval(tin, zout, b - nf_blocks, nz, &s_re[0][0]);
    }
}

extern "C" void kernel_launch(void* const* d_in, const int* in_sizes, int n_in,
                              void* d_out, int out_size, void* d_ws, size_t ws_size,
                              hipStream_t stream)
{
    const float* xre = (const float*)d_in[0];
    const float* xim = (const float*)d_in[1];
    const float* t   = (const float*)d_in[2];

    const size_t nfft = (size_t)in_sizes[0];          // 16384*1024
    const int nrows = (int)(nfft >> 10);              // 16384
    const int nz    = in_sizes[2];                    // 262144

    float* yre = (float*)d_out;
    float* yim = yre + nfft;
    float* z   = yre + 2 * nfft;

    const int nf_blocks = (nrows + 3) >> 2;
    const int z_blocks  = (nz + 255) >> 8;

    fused_kernel<<<nf_blocks + z_blocks, 256, 0, stream>>>(
        xre, xim, t, yre, yim, z, nf_blocks, nrows, nz);
}